// Round 3
// baseline (9218.359 us; speedup 1.0000x reference)
//
#include <hip/hip_runtime.h>
#include <hip/hip_bf16.h>

// LSTM B=1024 T=256 IN=64 H=512. Round 3: persistent kernel via PLAIN launch
// (cooperative API silently failed in R2) + hand-rolled monotonic grid
// barrier with explicit agent fences. Weights f16 in registers (144 VGPR),
// c state in registers, h rotates through 3 global buffers, LDS stages only
// the A tile (h||x_t) in two K-phases (42 KB, conflict-free).

#define TST   256
#define BATCH 1024
#define HID   512
#define INSZ  64
#define NCLS  10
#define LDST  328   // LDS row stride (elements): 328 % 64 == 8 -> dw stride % 32 == 4

typedef _Float16 f16x8  __attribute__((ext_vector_type(8)));
typedef float    f32x16 __attribute__((ext_vector_type(16)));

__device__ __forceinline__ float tanh_f(float x) {
    return 2.0f / (1.0f + __expf(-2.0f * x)) - 1.0f;
}

__device__ __forceinline__ f16x8 cvt8(float4 a, float4 b) {
    f16x8 o;
    o[0] = (_Float16)a.x; o[1] = (_Float16)a.y; o[2] = (_Float16)a.z; o[3] = (_Float16)a.w;
    o[4] = (_Float16)b.x; o[5] = (_Float16)b.y; o[6] = (_Float16)b.z; o[7] = (_Float16)b.w;
    return o;
}

__global__ __launch_bounds__(256, 1) void lstm_persist(
    const float* __restrict__ x,   const float* __restrict__ h0,
    const float* __restrict__ c0,  const float* __restrict__ Wih,
    const float* __restrict__ Whh, const float* __restrict__ bih,
    const float* __restrict__ bhh, _Float16* __restrict__ hb,
    unsigned* __restrict__ bar)
{
    __shared__ __align__(16) _Float16 As[64][LDST];   // 41984 B

    const int tid   = threadIdx.x;
    const int lane  = tid & 63;
    const int w     = tid >> 6;
    const int l31   = lane & 31;
    const int khalf = (lane >> 5) * 8;
    const int m0 = (int)(blockIdx.x >> 4) * 64;   // batch tile
    const int j0 = (int)(blockIdx.x & 15) * 32;   // hidden tile

    // column owned by this lane: np = w*32 + l31, interleaved n' = 4*jj + gate
    const int np   = w * 32 + l31;
    const int gate = np & 3;
    const int j    = j0 + (np >> 2);
    const int nrow = gate * HID + j;              // row in W_hh/W_ih

    // ---- B fragments in registers (loaded once; frag elem k = kt*16+khalf+e) ----
    f16x8 bfr[36];
    #pragma unroll
    for (int kt = 0; kt < 36; ++kt) {
        const int k0 = kt * 16 + khalf;
        const float* p = (kt < 32) ? (Whh + (size_t)nrow * HID + k0)
                                   : (Wih + (size_t)nrow * INSZ + (k0 - HID));
        float4 f0 = ((const float4*)p)[0];
        float4 f1 = ((const float4*)p)[1];
        bfr[kt] = cvt8(f0, f1);
    }
    const float bsv  = bih[nrow] + bhh[nrow];
    const bool  lead = (l31 & 3) == 0;            // gate==0 lane of each quad
    const float s    = (gate == 2) ? 2.0f : 1.0f; // tanh for g, sigmoid otherwise

    // ---- c state in registers (leader lanes only hold real values) ----
    float cr[2][16];
    #pragma unroll
    for (int a = 0; a < 2; ++a)
        #pragma unroll
        for (int r = 0; r < 16; ++r) {
            int row = (r & 3) + 8 * (r >> 2) + (lane >> 5) * 4 + a * 32;
            cr[a][r] = lead ? c0[(size_t)(m0 + row) * HID + j] : 0.0f;
        }

    const int rr = tid >> 2;       // staging: 4 threads per row
    const int q  = tid & 3;

    for (int t = 0; t < TST; ++t) {
        const _Float16* rb = hb + (size_t)((t + 2) % 3) * (BATCH * HID);
        _Float16*       wb = hb + (size_t)(t % 3) * (BATCH * HID);

        f32x16 acc[2];
        #pragma unroll
        for (int i = 0; i < 16; ++i) { acc[0][i] = 0.0f; acc[1][i] = 0.0f; }

        // ================= phase A: k = 0..319 =================
        if (t == 0) {
            #pragma unroll
            for (int i = 0; i < 5; ++i) {
                int c = q * 16 + i * 64;
                const float* p = h0 + (size_t)(m0 + rr) * HID + c;
                float4 f0 = ((const float4*)p)[0], f1 = ((const float4*)p)[1];
                float4 f2 = ((const float4*)p)[2], f3 = ((const float4*)p)[3];
                *(f16x8*)&As[rr][c]     = cvt8(f0, f1);
                *(f16x8*)&As[rr][c + 8] = cvt8(f2, f3);
            }
        } else {
            #pragma unroll
            for (int i = 0; i < 5; ++i) {
                int c = q * 16 + i * 64;
                const uint4* p = (const uint4*)(rb + (size_t)(m0 + rr) * HID + c);
                uint4 v0 = p[0], v1 = p[1];
                *(f16x8*)&As[rr][c]     = __builtin_bit_cast(f16x8, v0);
                *(f16x8*)&As[rr][c + 8] = __builtin_bit_cast(f16x8, v1);
            }
        }
        __syncthreads();
        #pragma unroll
        for (int kt = 0; kt < 20; ++kt) {
            f16x8 a0 = *(const f16x8*)&As[l31][kt * 16 + khalf];
            f16x8 a1 = *(const f16x8*)&As[32 + l31][kt * 16 + khalf];
            acc[0] = __builtin_amdgcn_mfma_f32_32x32x16_f16(a0, bfr[kt], acc[0], 0, 0, 0);
            acc[1] = __builtin_amdgcn_mfma_f32_32x32x16_f16(a1, bfr[kt], acc[1], 0, 0, 0);
        }
        __syncthreads();

        // ================= phase B: k = 320..575 (h 320..511, x 512..575) =========
        if (t == 0) {
            #pragma unroll
            for (int i = 0; i < 3; ++i) {
                int k = 320 + q * 16 + i * 64;
                const float* p = h0 + (size_t)(m0 + rr) * HID + k;
                float4 f0 = ((const float4*)p)[0], f1 = ((const float4*)p)[1];
                float4 f2 = ((const float4*)p)[2], f3 = ((const float4*)p)[3];
                *(f16x8*)&As[rr][k - 320]     = cvt8(f0, f1);
                *(f16x8*)&As[rr][k - 320 + 8] = cvt8(f2, f3);
            }
        } else {
            #pragma unroll
            for (int i = 0; i < 3; ++i) {
                int k = 320 + q * 16 + i * 64;
                const uint4* p = (const uint4*)(rb + (size_t)(m0 + rr) * HID + k);
                uint4 v0 = p[0], v1 = p[1];
                *(f16x8*)&As[rr][k - 320]     = __builtin_bit_cast(f16x8, v0);
                *(f16x8*)&As[rr][k - 320 + 8] = __builtin_bit_cast(f16x8, v1);
            }
        }
        {   // x_t slice, fp32 -> f16, lands at LDS cols 192..255 (k 512..575)
            const float* p = x + (size_t)(m0 + rr) * (TST * INSZ) + t * INSZ + q * 16;
            float4 f0 = ((const float4*)p)[0], f1 = ((const float4*)p)[1];
            float4 f2 = ((const float4*)p)[2], f3 = ((const float4*)p)[3];
            *(f16x8*)&As[rr][192 + q * 16]     = cvt8(f0, f1);
            *(f16x8*)&As[rr][192 + q * 16 + 8] = cvt8(f2, f3);
        }
        __syncthreads();
        #pragma unroll
        for (int kt = 20; kt < 36; ++kt) {
            f16x8 a0 = *(const f16x8*)&As[l31][(kt - 20) * 16 + khalf];
            f16x8 a1 = *(const f16x8*)&As[32 + l31][(kt - 20) * 16 + khalf];
            acc[0] = __builtin_amdgcn_mfma_f32_32x32x16_f16(a0, bfr[kt], acc[0], 0, 0, 0);
            acc[1] = __builtin_amdgcn_mfma_f32_32x32x16_f16(a1, bfr[kt], acc[1], 0, 0, 0);
        }

        // ================= epilogue: activations, c update, h store ==============
        #pragma unroll
        for (int a = 0; a < 2; ++a) {
            #pragma unroll
            for (int r = 0; r < 16; ++r) {
                float v = acc[a][r] + bsv;
                float e = __expf(-s * v);
                float act = s / (1.0f + e) - (s - 1.0f);   // sigmoid or tanh
                float g1 = __shfl_xor(act, 1);
                float g2 = __shfl_xor(act, 2);
                float g3 = __shfl_xor(act, 3);
                if (lead) {   // act=i, g1=f, g2=g, g3=o
                    float cn = g1 * cr[a][r] + act * g2;
                    cr[a][r] = cn;
                    float hn = g3 * tanh_f(cn);
                    int row = (r & 3) + 8 * (r >> 2) + (lane >> 5) * 4 + a * 32;
                    wb[(size_t)(m0 + row) * HID + j] = (_Float16)hn;
                }
            }
        }

        // ========== grid barrier (monotonic counter, plain launch) ==========
        __syncthreads();
        if (tid == 0) {
            __threadfence();   // release: write back dirty L2 (agent scope)
            __hip_atomic_fetch_add(bar, 1u, __ATOMIC_ACQ_REL, __HIP_MEMORY_SCOPE_AGENT);
            const unsigned target = 256u * (unsigned)(t + 1);
            while (__hip_atomic_load(bar, __ATOMIC_RELAXED, __HIP_MEMORY_SCOPE_AGENT) < target) {
                __builtin_amdgcn_s_sleep(2);
            }
            __threadfence();   // acquire: invalidate L1/stale L2 before h reads
        }
        __syncthreads();
    }
}

// ---------------- final linear: preds = hT @ W_lin^T + b_lin ----------------
__global__ __launch_bounds__(256) void final_kernel(
    const _Float16* __restrict__ h, const float* __restrict__ Wl,
    const float* __restrict__ bl, float* __restrict__ out)
{
    int i = blockIdx.x * 256 + threadIdx.x;
    if (i >= BATCH * NCLS) return;
    int b = i / NCLS, c = i - b * NCLS;
    const f16x8* hp = (const f16x8*)(h + (size_t)b * HID);
    const float4* wp = (const float4*)(Wl + (size_t)c * HID);
    float sacc = bl[c];
    #pragma unroll 4
    for (int k8 = 0; k8 < HID / 8; ++k8) {
        f16x8 hv = hp[k8];
        float4 w0 = wp[2 * k8], w1 = wp[2 * k8 + 1];
        sacc += (float)hv[0] * w0.x + (float)hv[1] * w0.y +
                (float)hv[2] * w0.z + (float)hv[3] * w0.w +
                (float)hv[4] * w1.x + (float)hv[5] * w1.y +
                (float)hv[6] * w1.z + (float)hv[7] * w1.w;
    }
    out[i] = sacc;
}

extern "C" void kernel_launch(void* const* d_in, const int* in_sizes, int n_in,
                              void* d_out, int out_size, void* d_ws, size_t ws_size,
                              hipStream_t stream)
{
    const float* x    = (const float*)d_in[0];
    const float* h0   = (const float*)d_in[1];
    const float* c0   = (const float*)d_in[2];
    const float* Wih  = (const float*)d_in[3];
    const float* Whh  = (const float*)d_in[4];
    const float* bih  = (const float*)d_in[5];
    const float* bhh  = (const float*)d_in[6];
    const float* Wlin = (const float*)d_in[7];
    const float* blin = (const float*)d_in[8];
    float* out = (float*)d_out;

    unsigned* bar = (unsigned*)d_ws;
    _Float16* hb  = (_Float16*)((char*)d_ws + 4096);   // 3 x 1 MB h buffers

    hipMemsetAsync(d_ws, 0, 4096, stream);             // zero barrier counter

    // 256 blocks on 256 CUs at 1 block/CU (launch_bounds(256,1), 42KB LDS):
    // all blocks co-resident -> grid barrier is safe with a plain launch.
    lstm_persist<<<256, 256, 0, stream>>>(x, h0, c0, Wih, Whh, bih, bhh, hb, bar);

    // step t=255 wrote buffer (255 % 3) == 0 -> hb
    final_kernel<<<(BATCH * NCLS + 255) / 256, 256, 0, stream>>>(hb, Wlin, blin, out);
}

// Round 4
// 3280.563 us; speedup vs baseline: 2.8100x; 2.8100x over previous
//
#include <hip/hip_runtime.h>
#include <hip/hip_bf16.h>

// LSTM B=1024 T=256 IN=64 H=512. Round 4: persistent kernel, plain launch.
// Fix vs R3 (9.2ms, 35us/step, all pipes idle): the per-step __threadfence()
// pair emitted buffer_wbl2/buffer_inv = full 4MB L2 tag walks, 64 walks per
// XCD per step. Now: NO fences. h exchange uses relaxed AGENT-scope 8B
// atomics (sc0 sc1 per-instruction coherence, no walks); grid barrier split
// into 16 independent 16-block m-group barriers (padded counters).
// Weights f16 in registers (72 VGPR), c in registers, 3-buffer h rotation.

#define TST   256
#define BATCH 1024
#define HID   512
#define INSZ  64
#define NCLS  10
#define LDST  328   // LDS row stride (elem): 328 % 64 == 8 -> dw stride % 32 == 4

typedef _Float16 f16x8  __attribute__((ext_vector_type(8)));
typedef float    f32x16 __attribute__((ext_vector_type(16)));
typedef unsigned long long u64;

__device__ __forceinline__ float tanh_f(float x) {
    return 2.0f / (1.0f + __expf(-2.0f * x)) - 1.0f;
}

__device__ __forceinline__ f16x8 cvt8(float4 a, float4 b) {
    f16x8 o;
    o[0] = (_Float16)a.x; o[1] = (_Float16)a.y; o[2] = (_Float16)a.z; o[3] = (_Float16)a.w;
    o[4] = (_Float16)b.x; o[5] = (_Float16)b.y; o[6] = (_Float16)b.z; o[7] = (_Float16)b.w;
    return o;
}

__global__ __launch_bounds__(256, 1) void lstm_persist(
    const float* __restrict__ x,   const float* __restrict__ h0,
    const float* __restrict__ c0,  const float* __restrict__ Wih,
    const float* __restrict__ Whh, const float* __restrict__ bih,
    const float* __restrict__ bhh, _Float16* __restrict__ hb,
    unsigned* __restrict__ bar)
{
    __shared__ __align__(16) _Float16 As[64][LDST];   // 41984 B

    const int tid   = threadIdx.x;
    const int lane  = tid & 63;
    const int w     = tid >> 6;
    const int l31   = lane & 31;
    const int khalf = (lane >> 5) * 8;

    // group = blockIdx&15 -> members share blockIdx%8 (same-XCD heuristic)
    const int g  = (int)(blockIdx.x & 15);
    const int m0 = g * 64;                        // batch tile
    const int j0 = (int)(blockIdx.x >> 4) * 32;   // hidden tile
    unsigned* cnt = bar + g * 64;                 // 256B-padded per-group counter

    // column owned by this lane: np = w*32 + l31, interleaved n' = 4*jj + gate
    const int np   = w * 32 + l31;
    const int gate = np & 3;
    const int j    = j0 + (np >> 2);
    const int nrow = gate * HID + j;              // row in W_hh / W_ih

    // ---- B fragments in registers (loaded once) ----
    f16x8 bfr[36];
    #pragma unroll
    for (int kt = 0; kt < 36; ++kt) {
        const int k0 = kt * 16 + khalf;
        const float* p = (kt < 32) ? (Whh + (size_t)nrow * HID + k0)
                                   : (Wih + (size_t)nrow * INSZ + (k0 - HID));
        float4 f0 = ((const float4*)p)[0];
        float4 f1 = ((const float4*)p)[1];
        bfr[kt] = cvt8(f0, f1);
    }
    const float bsv = bih[nrow] + bhh[nrow];
    const float s   = (gate == 2) ? 2.0f : 1.0f;  // tanh for g, sigmoid otherwise
    const int rowhi = (lane >> 5) * 4;

    // ---- c state in registers (only lead lanes' values are meaningful) ----
    float cr[2][16];
    #pragma unroll
    for (int a = 0; a < 2; ++a)
        #pragma unroll
        for (int r = 0; r < 16; ++r) {
            int row = (r & 3) + 8 * (r >> 2) + rowhi + a * 32;
            cr[a][r] = c0[(size_t)(m0 + row) * HID + j];
        }

    const int rr = tid >> 2;       // staging: 4 threads per row
    const int q  = tid & 3;

    for (int t = 0; t < TST; ++t) {
        const _Float16* rb = hb + (size_t)((t + 2) % 3) * (BATCH * HID);
        _Float16*       wb = hb + (size_t)(t % 3) * (BATCH * HID);

        // ---- x_t prefetch (plain cached loads; latency hides under h staging)
        float4 xr[4];
        {
            const float* xp = x + (size_t)(m0 + rr) * (TST * INSZ) + t * INSZ + q * 16;
            xr[0] = ((const float4*)xp)[0]; xr[1] = ((const float4*)xp)[1];
            xr[2] = ((const float4*)xp)[2]; xr[3] = ((const float4*)xp)[3];
        }

        // ================= phase A: k = 0..319 =================
        if (t == 0) {
            #pragma unroll
            for (int i = 0; i < 5; ++i) {
                int c = q * 16 + i * 64;
                const float* p = h0 + (size_t)(m0 + rr) * HID + c;
                float4 f0 = ((const float4*)p)[0], f1 = ((const float4*)p)[1];
                float4 f2 = ((const float4*)p)[2], f3 = ((const float4*)p)[3];
                *(f16x8*)&As[rr][c]     = cvt8(f0, f1);
                *(f16x8*)&As[rr][c + 8] = cvt8(f2, f3);
            }
        } else {
            // coherent (sc0 sc1) 8B loads, bypass stale L1/L2 — no fences needed
            const u64* rbq = (const u64*)(rb + (size_t)(m0 + rr) * HID);
            u64 ta[20];
            #pragma unroll
            for (int i = 0; i < 5; ++i)
                #pragma unroll
                for (int u = 0; u < 4; ++u)
                    ta[i * 4 + u] = __hip_atomic_load(
                        &rbq[(q * 16 + i * 64) / 4 + u],
                        __ATOMIC_RELAXED, __HIP_MEMORY_SCOPE_AGENT);
            #pragma unroll
            for (int i = 0; i < 5; ++i)
                #pragma unroll
                for (int u = 0; u < 4; ++u)
                    *(u64*)&As[rr][q * 16 + i * 64 + u * 4] = ta[i * 4 + u];
        }
        __syncthreads();

        f32x16 acc[2];
        #pragma unroll
        for (int i = 0; i < 16; ++i) { acc[0][i] = 0.0f; acc[1][i] = 0.0f; }

        #pragma unroll
        for (int kt = 0; kt < 20; ++kt) {
            f16x8 a0 = *(const f16x8*)&As[l31][kt * 16 + khalf];
            f16x8 a1 = *(const f16x8*)&As[32 + l31][kt * 16 + khalf];
            acc[0] = __builtin_amdgcn_mfma_f32_32x32x16_f16(a0, bfr[kt], acc[0], 0, 0, 0);
            acc[1] = __builtin_amdgcn_mfma_f32_32x32x16_f16(a1, bfr[kt], acc[1], 0, 0, 0);
        }
        __syncthreads();

        // ============ phase B: k = 320..575 (h 320..511, x 512..575) ============
        if (t == 0) {
            #pragma unroll
            for (int i = 0; i < 3; ++i) {
                int k = 320 + q * 16 + i * 64;
                const float* p = h0 + (size_t)(m0 + rr) * HID + k;
                float4 f0 = ((const float4*)p)[0], f1 = ((const float4*)p)[1];
                float4 f2 = ((const float4*)p)[2], f3 = ((const float4*)p)[3];
                *(f16x8*)&As[rr][k - 320]     = cvt8(f0, f1);
                *(f16x8*)&As[rr][k - 320 + 8] = cvt8(f2, f3);
            }
        } else {
            const u64* rbq = (const u64*)(rb + (size_t)(m0 + rr) * HID);
            u64 tb[12];
            #pragma unroll
            for (int i = 0; i < 3; ++i)
                #pragma unroll
                for (int u = 0; u < 4; ++u)
                    tb[i * 4 + u] = __hip_atomic_load(
                        &rbq[(320 + q * 16 + i * 64) / 4 + u],
                        __ATOMIC_RELAXED, __HIP_MEMORY_SCOPE_AGENT);
            #pragma unroll
            for (int i = 0; i < 3; ++i)
                #pragma unroll
                for (int u = 0; u < 4; ++u)
                    *(u64*)&As[rr][q * 16 + i * 64 + u * 4] = tb[i * 4 + u];
        }
        {   // x_t slice -> LDS cols 192..255 (k 512..575)
            *(f16x8*)&As[rr][192 + q * 16]     = cvt8(xr[0], xr[1]);
            *(f16x8*)&As[rr][192 + q * 16 + 8] = cvt8(xr[2], xr[3]);
        }
        __syncthreads();
        #pragma unroll
        for (int kt = 20; kt < 36; ++kt) {
            f16x8 a0 = *(const f16x8*)&As[l31][(kt - 20) * 16 + khalf];
            f16x8 a1 = *(const f16x8*)&As[32 + l31][(kt - 20) * 16 + khalf];
            acc[0] = __builtin_amdgcn_mfma_f32_32x32x16_f16(a0, bfr[kt], acc[0], 0, 0, 0);
            acc[1] = __builtin_amdgcn_mfma_f32_32x32x16_f16(a1, bfr[kt], acc[1], 0, 0, 0);
        }

        // ===== epilogue: gates -> c,h; pack 4 units/quad -> one 8B coherent store
        #pragma unroll
        for (int a = 0; a < 2; ++a) {
            #pragma unroll
            for (int r = 0; r < 16; ++r) {
                float v = acc[a][r] + bsv;
                float e = __expf(-s * v);
                float act = s / (1.0f + e) - (s - 1.0f);   // sigmoid or tanh
                float g1 = __shfl_xor(act, 1);
                float g2 = __shfl_xor(act, 2);
                float g3 = __shfl_xor(act, 3);
                // lead lanes (l31%4==0): act=i, g1=f, g2=g, g3=o
                float cn = g1 * cr[a][r] + act * g2;
                cr[a][r] = cn;
                float hn = g3 * tanh_f(cn);
                unsigned hu = (unsigned)__builtin_bit_cast(unsigned short, (_Float16)hn);
                unsigned pk = hu | (__shfl_xor(hu, 4) << 16);     // (j, j+1)
                u64 v4 = (u64)pk | ((u64)__shfl_xor(pk, 8) << 32); // (j..j+3)
                if ((l31 & 15) == 0) {
                    int row = (r & 3) + 8 * (r >> 2) + rowhi + a * 32;
                    __hip_atomic_store((u64*)&wb[(size_t)(m0 + row) * HID + j],
                                       v4, __ATOMIC_RELAXED, __HIP_MEMORY_SCOPE_AGENT);
                }
            }
        }

        // ===== m-group barrier: 16 blocks, relaxed atomics, no cache walks =====
        __syncthreads();   // drains each wave's vmcnt -> h stores at coherence point
        if (tid == 0) {
            __hip_atomic_fetch_add(cnt, 1u, __ATOMIC_RELAXED, __HIP_MEMORY_SCOPE_AGENT);
            const unsigned target = 16u * (unsigned)(t + 1);
            while (__hip_atomic_load(cnt, __ATOMIC_RELAXED, __HIP_MEMORY_SCOPE_AGENT) < target)
                __builtin_amdgcn_s_sleep(1);
        }
        __syncthreads();
    }
}

// ---------------- final linear: preds = hT @ W_lin^T + b_lin ----------------
__global__ __launch_bounds__(256) void final_kernel(
    const _Float16* __restrict__ h, const float* __restrict__ Wl,
    const float* __restrict__ bl, float* __restrict__ out)
{
    int i = blockIdx.x * 256 + threadIdx.x;
    if (i >= BATCH * NCLS) return;
    int b = i / NCLS, c = i - b * NCLS;
    const f16x8* hp = (const f16x8*)(h + (size_t)b * HID);
    const float4* wp = (const float4*)(Wl + (size_t)c * HID);
    float sacc = bl[c];
    #pragma unroll 4
    for (int k8 = 0; k8 < HID / 8; ++k8) {
        f16x8 hv = hp[k8];
        float4 w0 = wp[2 * k8], w1 = wp[2 * k8 + 1];
        sacc += (float)hv[0] * w0.x + (float)hv[1] * w0.y +
                (float)hv[2] * w0.z + (float)hv[3] * w0.w +
                (float)hv[4] * w1.x + (float)hv[5] * w1.y +
                (float)hv[6] * w1.z + (float)hv[7] * w1.w;
    }
    out[i] = sacc;
}

extern "C" void kernel_launch(void* const* d_in, const int* in_sizes, int n_in,
                              void* d_out, int out_size, void* d_ws, size_t ws_size,
                              hipStream_t stream)
{
    const float* x    = (const float*)d_in[0];
    const float* h0   = (const float*)d_in[1];
    const float* c0   = (const float*)d_in[2];
    const float* Wih  = (const float*)d_in[3];
    const float* Whh  = (const float*)d_in[4];
    const float* bih  = (const float*)d_in[5];
    const float* bhh  = (const float*)d_in[6];
    const float* Wlin = (const float*)d_in[7];
    const float* blin = (const float*)d_in[8];
    float* out = (float*)d_out;

    unsigned* bar = (unsigned*)d_ws;                   // 16 counters, 256B apart
    _Float16* hb  = (_Float16*)((char*)d_ws + 4096);   // 3 x 1 MB h buffers

    hipMemsetAsync(d_ws, 0, 4096, stream);             // zero group counters

    // 256 blocks, 1/CU (launch_bounds(256,1), 42KB LDS) -> all co-resident.
    lstm_persist<<<256, 256, 0, stream>>>(x, h0, c0, Wih, Whh, bih, bhh, hb, bar);

    // step t=255 wrote buffer (255 % 3) == 0 -> hb
    final_kernel<<<(BATCH * NCLS + 255) / 256, 256, 0, stream>>>(hb, Wlin, blin, out);
}

// Round 6
// 1881.374 us; speedup vs baseline: 4.8998x; 1.7437x over previous
//
#include <hip/hip_runtime.h>
#include <hip/hip_bf16.h>

// LSTM B=1024 T=256 IN=64 H=512. Round 6: R5 with the DPP pack direction
// FIXED: row_shl (0x104/0x108) brings lane i+N -> lane i (row_shr was the
// reverse and zeroed 3/4 of h). Structure: persistent kernel, plain launch,
// 32 m-groups x 8 j-blocks (h replication 8x), single-phase A staging
// (37KB LDS, one MALL exposure), 1 A-read feeds 2 MFMAs, DPP epilogue
// (quad_perm gate combine + row_shl pack), weights f16 register-resident.

#define TST   256
#define BATCH 1024
#define HID   512
#define INSZ  64
#define NCLS  10
#define LDSTR 584   // elem stride: 1168 B = 292 dw = 4 mod 32 -> conflict-free

typedef _Float16 f16x8  __attribute__((ext_vector_type(8)));
typedef float    f32x16 __attribute__((ext_vector_type(16)));
typedef unsigned long long u64;

__device__ __forceinline__ float tanh_f(float x) {
    return 2.0f / (1.0f + __expf(-2.0f * x)) - 1.0f;
}

__device__ __forceinline__ f16x8 cvt8(float4 a, float4 b) {
    f16x8 o;
    o[0] = (_Float16)a.x; o[1] = (_Float16)a.y; o[2] = (_Float16)a.z; o[3] = (_Float16)a.w;
    o[4] = (_Float16)b.x; o[5] = (_Float16)b.y; o[6] = (_Float16)b.z; o[7] = (_Float16)b.w;
    return o;
}

__device__ __forceinline__ u64 cvt4_u64(float4 a) {
    _Float16 h[4] = {(_Float16)a.x, (_Float16)a.y, (_Float16)a.z, (_Float16)a.w};
    u64 r;
    __builtin_memcpy(&r, h, 8);
    return r;
}

template <int CTRL>
__device__ __forceinline__ float dpp_f(float v) {
    return __builtin_bit_cast(float,
        __builtin_amdgcn_mov_dpp(__builtin_bit_cast(int, v), CTRL, 0xF, 0xF, true));
}
template <int CTRL>
__device__ __forceinline__ unsigned dpp_u(unsigned v) {
    return (unsigned)__builtin_amdgcn_mov_dpp((int)v, CTRL, 0xF, 0xF, true);
}
// DPP ctrls: quad_perm xor1=0xB1, xor2=0x4E, xor3=0x1B (symmetric);
// row_shl:4=0x104, row_shl:8=0x108 (dst lane i <- src lane i+N).

__global__ __launch_bounds__(256, 1) void lstm_persist(
    const float* __restrict__ x,   const float* __restrict__ h0,
    const float* __restrict__ c0,  const float* __restrict__ Wih,
    const float* __restrict__ Whh, const float* __restrict__ bih,
    const float* __restrict__ bhh, _Float16* __restrict__ hb,
    unsigned* __restrict__ bar)
{
    __shared__ __align__(16) _Float16 As[32][LDSTR];   // 37376 B

    const int tid   = threadIdx.x;
    const int lane  = tid & 63;
    const int w     = tid >> 6;        // wave 0..3
    const int l31   = lane & 31;
    const int khalf = (lane >> 5) * 8;
    const int g  = (int)(blockIdx.x >> 3);   // m-group 0..31
    const int jb = (int)(blockIdx.x & 7);    // j-block 0..7
    const int m0 = g * 32;
    const int j0 = jb * 64;
    unsigned* cnt = bar + g * 64;            // 256B-padded per-group counter

    const int gate = l31 & 3;                // nt*32 preserves np&3
    int jcol[2], nrow[2];
    #pragma unroll
    for (int nt = 0; nt < 2; ++nt) {
        int np = w * 64 + nt * 32 + l31;
        jcol[nt] = j0 + (np >> 2);
        nrow[nt] = gate * HID + jcol[nt];
    }

    // ---- B fragments in registers (one-time): bfr[nt][kt] ----
    f16x8 bfr[2][36];
    #pragma unroll
    for (int nt = 0; nt < 2; ++nt)
        #pragma unroll
        for (int kt = 0; kt < 36; ++kt) {
            const int k0 = kt * 16 + khalf;
            const float* p = (kt < 32) ? (Whh + (size_t)nrow[nt] * HID + k0)
                                       : (Wih + (size_t)nrow[nt] * INSZ + (k0 - HID));
            float4 f0 = ((const float4*)p)[0];
            float4 f1 = ((const float4*)p)[1];
            bfr[nt][kt] = cvt8(f0, f1);
        }
    float bsv[2];
    bsv[0] = bih[nrow[0]] + bhh[nrow[0]];
    bsv[1] = bih[nrow[1]] + bhh[nrow[1]];
    const float s   = (gate == 2) ? 2.0f : 1.0f;   // tanh for g, sigmoid otherwise
    const int rowhi = (lane >> 5) * 4;

    // ---- c state in registers (lead lanes l31%4==0 hold the real values) ----
    float cr[2][16];
    #pragma unroll
    for (int nt = 0; nt < 2; ++nt)
        #pragma unroll
        for (int r = 0; r < 16; ++r) {
            int row = (r & 3) + 8 * (r >> 2) + rowhi;
            cr[nt][r] = c0[(size_t)(m0 + row) * HID + jcol[nt]];
        }

    const int rr = tid >> 3;       // staging: 8 threads per row (32 rows)
    const int q  = tid & 7;

    for (int t = 0; t < TST; ++t) {
        const _Float16* rb = hb + (size_t)((t + 2) % 3) * (BATCH * HID);
        _Float16*       wb = hb + (size_t)(t % 3) * (BATCH * HID);

        // ---- issue ALL staging loads up front (x + h), then write LDS ----
        float4 x0, x1;
        {
            const float* xp = x + (size_t)(m0 + rr) * (TST * INSZ) + t * INSZ + q * 8;
            x0 = ((const float4*)xp)[0];
            x1 = ((const float4*)xp)[1];
        }
        if (t == 0) {
            u64 hv[16];
            #pragma unroll
            for (int u = 0; u < 16; ++u) {
                float4 f = *(const float4*)(h0 + (size_t)(m0 + rr) * HID + q * 4 + u * 32);
                hv[u] = cvt4_u64(f);
            }
            #pragma unroll
            for (int u = 0; u < 16; ++u)
                *(u64*)&As[rr][q * 4 + u * 32] = hv[u];
        } else {
            // coherent (sc0 sc1) 8B loads from the MALL — no fences needed
            const u64* rbq = (const u64*)(rb + (size_t)(m0 + rr) * HID);
            u64 hv[16];
            #pragma unroll
            for (int u = 0; u < 16; ++u)
                hv[u] = __hip_atomic_load(&rbq[q + u * 8],
                                          __ATOMIC_RELAXED, __HIP_MEMORY_SCOPE_AGENT);
            #pragma unroll
            for (int u = 0; u < 16; ++u)
                *(u64*)&As[rr][q * 4 + u * 32] = hv[u];
        }
        *(f16x8*)&As[rr][512 + q * 8] = cvt8(x0, x1);   // x_t -> k 512..575
        __syncthreads();

        // ---- MFMA: 36 k-tiles, 1 A-read feeds both n-tiles ----
        f32x16 acc[2];
        #pragma unroll
        for (int i = 0; i < 16; ++i) { acc[0][i] = 0.0f; acc[1][i] = 0.0f; }
        #pragma unroll
        for (int kt = 0; kt < 36; ++kt) {
            f16x8 af = *(const f16x8*)&As[l31][kt * 16 + khalf];
            acc[0] = __builtin_amdgcn_mfma_f32_32x32x16_f16(af, bfr[0][kt], acc[0], 0, 0, 0);
            acc[1] = __builtin_amdgcn_mfma_f32_32x32x16_f16(af, bfr[1][kt], acc[1], 0, 0, 0);
        }

        // ---- epilogue: DPP gate combine (VALU, no DS), c/h update, 8B stores ----
        #pragma unroll
        for (int nt = 0; nt < 2; ++nt) {
            #pragma unroll
            for (int r = 0; r < 16; ++r) {
                float v = acc[nt][r] + bsv[nt];
                float e = __expf(-s * v);
                float act = s / (1.0f + e) - (s - 1.0f);   // sigmoid or tanh
                float fu = dpp_f<0xB1>(act);   // quad xor1: f
                float gu = dpp_f<0x4E>(act);   // quad xor2: g
                float ou = dpp_f<0x1B>(act);   // quad xor3: o
                float cn = fu * cr[nt][r] + act * gu;
                cr[nt][r] = cn;
                float hn = ou * tanh_f(cn);
                unsigned hu = (unsigned)__builtin_bit_cast(unsigned short, (_Float16)hn);
                unsigned pk = hu | (dpp_u<0x104>(hu) << 16);          // <- lane+4
                u64 v4 = (u64)pk | ((u64)dpp_u<0x108>(pk) << 32);     // <- lane+8
                if ((l31 & 15) == 0) {
                    int row = (r & 3) + 8 * (r >> 2) + rowhi;
                    __hip_atomic_store((u64*)&wb[(size_t)(m0 + row) * HID + jcol[nt]],
                                       v4, __ATOMIC_RELAXED, __HIP_MEMORY_SCOPE_AGENT);
                }
            }
        }

        // ---- m-group barrier: 8 blocks, relaxed atomics ----
        __syncthreads();   // drains vmcnt -> h stores acked at coherence point
        if (tid == 0) {
            __hip_atomic_fetch_add(cnt, 1u, __ATOMIC_RELAXED, __HIP_MEMORY_SCOPE_AGENT);
            const unsigned target = 8u * (unsigned)(t + 1);
            while (__hip_atomic_load(cnt, __ATOMIC_RELAXED, __HIP_MEMORY_SCOPE_AGENT) < target)
                __builtin_amdgcn_s_sleep(1);
        }
        __syncthreads();
    }
}

// ---------------- final linear: preds = hT @ W_lin^T + b_lin ----------------
__global__ __launch_bounds__(256) void final_kernel(
    const _Float16* __restrict__ h, const float* __restrict__ Wl,
    const float* __restrict__ bl, float* __restrict__ out)
{
    int i = blockIdx.x * 256 + threadIdx.x;
    if (i >= BATCH * NCLS) return;
    int b = i / NCLS, c = i - b * NCLS;
    const f16x8* hp = (const f16x8*)(h + (size_t)b * HID);
    const float4* wp = (const float4*)(Wl + (size_t)c * HID);
    float sacc = bl[c];
    #pragma unroll 4
    for (int k8 = 0; k8 < HID / 8; ++k8) {
        f16x8 hv = hp[k8];
        float4 w0 = wp[2 * k8], w1 = wp[2 * k8 + 1];
        sacc += (float)hv[0] * w0.x + (float)hv[1] * w0.y +
                (float)hv[2] * w0.z + (float)hv[3] * w0.w +
                (float)hv[4] * w1.x + (float)hv[5] * w1.y +
                (float)hv[6] * w1.z + (float)hv[7] * w1.w;
    }
    out[i] = sacc;
}

extern "C" void kernel_launch(void* const* d_in, const int* in_sizes, int n_in,
                              void* d_out, int out_size, void* d_ws, size_t ws_size,
                              hipStream_t stream)
{
    const float* x    = (const float*)d_in[0];
    const float* h0   = (const float*)d_in[1];
    const float* c0   = (const float*)d_in[2];
    const float* Wih  = (const float*)d_in[3];
    const float* Whh  = (const float*)d_in[4];
    const float* bih  = (const float*)d_in[5];
    const float* bhh  = (const float*)d_in[6];
    const float* Wlin = (const float*)d_in[7];
    const float* blin = (const float*)d_in[8];
    float* out = (float*)d_out;

    unsigned* bar = (unsigned*)d_ws;                   // 32 counters, 256B apart
    _Float16* hb  = (_Float16*)((char*)d_ws + 8192);   // 3 x 1 MB h buffers

    hipMemsetAsync(d_ws, 0, 8192, stream);             // zero group counters

    // 256 blocks, 1/CU (launch_bounds(256,1), 37KB LDS) -> all co-resident.
    lstm_persist<<<256, 256, 0, stream>>>(x, h0, c0, Wih, Whh, bih, bhh, hb, bar);

    // step t=255 wrote buffer (255 % 3) == 0 -> hb
    final_kernel<<<(BATCH * NCLS + 255) / 256, 256, 0, stream>>>(hb, Wlin, blin, out);
}